// Round 9
// baseline (76.863 us; speedup 1.0000x reference)
//
#include <hip/hip_runtime.h>

// ChannelAttention b=2, n=4096, c=32 fp32.
// S = X X^T (Gram), softmax over j per row i, out[j,c] = sum_i attn[i,j] x[i,c]; out*g + x.
//
// R11 -> R12 (ILP theory): R6's -13.6us was 3x its BW prediction -> the excess
// was added per-wave ILP (2 independent S->exp->transpose->PV chains). R11
// added j-width but PHASED it (2 serial groups of 2) -> only the small BW win.
// This round: identical to R11 except k2's phases are MERGED -> 4 independent
// chains in one scheduling region (8 S-MFMA, 32 exp, 4 transposes, 8 PV-MFMA).
// k2 drops the ",2" occupancy bound (more live regs; R7 proved extra waves
// don't help at constant traffic, so 1 block/CU is acceptable).
//
// MFMA plan (16x16x32 f16, K = c = 32):
//  k0: convert x -> Xf16 [b][n][c] and XT2 f16 [b][n/32][c][32]; zero out
//  k1: Z_i = sum_j exp(s_ij - 48); store c2[i] = -log2(Z_i) - 48*log2e
//  k2: per (64-j, i-half) tile: S-MFMA -> attn=exp2(s*log2e + c2[i]) (fp16)
//      -> in-register quad shuffle -> PV-MFMA -> LDS 8-wave reduce -> atomicAdd.

typedef _Float16 half8 __attribute__((ext_vector_type(8)));
typedef _Float16 half4v __attribute__((ext_vector_type(4)));
typedef _Float16 half2v __attribute__((ext_vector_type(2)));
typedef float float4v __attribute__((ext_vector_type(4)));
typedef int int4v __attribute__((ext_vector_type(4)));

#define NN 4096
#define CC 32
#define L2E 1.44269504f
#define SHIFT 48.0f

// ---------------- k0: fp32 -> fp16 row-major + fp16 block-transposed + zero out ----------------
__global__ __launch_bounds__(256) void k_convert(const float* __restrict__ x,
                                                 _Float16* __restrict__ xf,
                                                 _Float16* __restrict__ xt,
                                                 float* __restrict__ out) {
    const int t = blockIdx.x * 256 + threadIdx.x;   // 65536 threads
    const int n  = t & 4095;
    const int cg = (t >> 12) & 7;
    const int b  = t >> 15;
    const int row = (b << 12) | n;
    const float4* src = (const float4*)(x + (size_t)row * CC + cg * 4);
    float4 v = *src;
    _Float16 h0 = (_Float16)v.x, h1 = (_Float16)v.y, h2 = (_Float16)v.z, h3 = (_Float16)v.w;
    *(half4v*)(xf + (size_t)row * CC + cg * 4) = (half4v){h0, h1, h2, h3};
    // XT2[b][n>>5][c][n&31]; consecutive lanes (consecutive n) -> consecutive addrs
    _Float16* p = xt + (size_t)b * CC * NN + (size_t)(n >> 5) * (CC * 32) + cg * 4 * 32 + (n & 31);
    p[0]  = h0;
    p[32] = h1;
    p[64] = h2;
    p[96] = h3;
    // zero d_out for k2's atomicAdd epilogue (262144 floats / 65536 threads = 4)
    *(float4*)(out + (size_t)t * 4) = (float4){0.f, 0.f, 0.f, 0.f};
}

// ---------------- k1: per-row shifted sum-of-exp -> c2[i] ----------------
// Block = 512 threads (8 waves), one 32-row i-tile (2 A-frags); each wave covers
// 512 j's, 4 B-tiles/iter, 1-deep prefetch. 256 blocks total.  [EXACTLY R10/R11]
__global__ __launch_bounds__(512, 2) void k_pass1(const _Float16* __restrict__ xf,
                                                  float* __restrict__ c2out) {
    const int tid = threadIdx.x;
    const int wave = tid >> 6, lane = tid & 63;
    const int quad = lane >> 4, l15 = lane & 15;
    const int b = blockIdx.x >> 7;
    const int i0 = (blockIdx.x & 127) * 32;
    const _Float16* xb = xf + (size_t)b * NN * CC;

    const half8 af0 = *(const half8*)(xb + (size_t)(i0 + l15) * CC + quad * 8);
    const half8 af1 = *(const half8*)(xb + (size_t)(i0 + 16 + l15) * CC + quad * 8);
    const float4v zf = {0.f, 0.f, 0.f, 0.f};
    float z0[4] = {0.f, 0.f, 0.f, 0.f};
    float z1[4] = {0.f, 0.f, 0.f, 0.f};
    const float c2c = -SHIFT * L2E;

    const int jbase = wave * 512;
    half8 b0 = *(const half8*)(xb + (size_t)(jbase + l15) * CC + quad * 8);
    half8 b1 = *(const half8*)(xb + (size_t)(jbase + 16 + l15) * CC + quad * 8);
    half8 b2 = *(const half8*)(xb + (size_t)(jbase + 32 + l15) * CC + quad * 8);
    half8 b3 = *(const half8*)(xb + (size_t)(jbase + 48 + l15) * CC + quad * 8);

    for (int jt = 0; jt < 8; ++jt) {           // 8 iters x 4 tiles x 16 j = 512 j
        const int jn = jbase + ((jt + 1) & 7) * 64;   // wraps on last iter (harmless)
        half8 n0 = *(const half8*)(xb + (size_t)(jn + l15) * CC + quad * 8);
        half8 n1 = *(const half8*)(xb + (size_t)(jn + 16 + l15) * CC + quad * 8);
        half8 n2 = *(const half8*)(xb + (size_t)(jn + 32 + l15) * CC + quad * 8);
        half8 n3 = *(const half8*)(xb + (size_t)(jn + 48 + l15) * CC + quad * 8);

        float4v s00 = __builtin_amdgcn_mfma_f32_16x16x32_f16(af0, b0, zf, 0, 0, 0);
        float4v s01 = __builtin_amdgcn_mfma_f32_16x16x32_f16(af0, b1, zf, 0, 0, 0);
        float4v s02 = __builtin_amdgcn_mfma_f32_16x16x32_f16(af0, b2, zf, 0, 0, 0);
        float4v s03 = __builtin_amdgcn_mfma_f32_16x16x32_f16(af0, b3, zf, 0, 0, 0);
        float4v s10 = __builtin_amdgcn_mfma_f32_16x16x32_f16(af1, b0, zf, 0, 0, 0);
        float4v s11 = __builtin_amdgcn_mfma_f32_16x16x32_f16(af1, b1, zf, 0, 0, 0);
        float4v s12 = __builtin_amdgcn_mfma_f32_16x16x32_f16(af1, b2, zf, 0, 0, 0);
        float4v s13 = __builtin_amdgcn_mfma_f32_16x16x32_f16(af1, b3, zf, 0, 0, 0);
#pragma unroll
        for (int r = 0; r < 4; ++r) {
            z0[r] += __builtin_amdgcn_exp2f(fmaf(s00[r], L2E, c2c));
            z0[r] += __builtin_amdgcn_exp2f(fmaf(s01[r], L2E, c2c));
            z0[r] += __builtin_amdgcn_exp2f(fmaf(s02[r], L2E, c2c));
            z0[r] += __builtin_amdgcn_exp2f(fmaf(s03[r], L2E, c2c));
            z1[r] += __builtin_amdgcn_exp2f(fmaf(s10[r], L2E, c2c));
            z1[r] += __builtin_amdgcn_exp2f(fmaf(s11[r], L2E, c2c));
            z1[r] += __builtin_amdgcn_exp2f(fmaf(s12[r], L2E, c2c));
            z1[r] += __builtin_amdgcn_exp2f(fmaf(s13[r], L2E, c2c));
        }
        b0 = n0; b1 = n1; b2 = n2; b3 = n3;
    }
    // combine over the 16 j-lanes within each quad group
#pragma unroll
    for (int off = 1; off <= 8; off <<= 1) {
#pragma unroll
        for (int r = 0; r < 4; ++r) {
            z0[r] += __shfl_xor(z0[r], off, 64);
            z1[r] += __shfl_xor(z1[r], off, 64);
        }
    }
    __shared__ float zw[8][32];
    if (l15 == 0) {
#pragma unroll
        for (int r = 0; r < 4; ++r) {
            zw[wave][quad * 4 + r]      = z0[r];
            zw[wave][16 + quad * 4 + r] = z1[r];
        }
    }
    __syncthreads();
    if (tid < 32) {
        float zs = 0.f;
#pragma unroll
        for (int w = 0; w < 8; ++w) zs += zw[w][tid];
        c2out[b * NN + i0 + tid] = -(__builtin_amdgcn_logf(zs) + SHIFT * L2E);
    }
}

// ---------------- k2: output pass (64-j tile x i-half, flat 4-chain body) ----------------
// 256 blocks: blockIdx = b(1) | jt(6) | ih(1). Block covers j0=jt*64 (4 B-frags)
// and i in [ih*2048, +2048): wave w covers 256 i = 8 iters x 32 i. All 4
// j-subtile chains issued in ONE region (no phasing) for 4-way ILP in the
// S->exp->cvt->bpermute->PV dependency chain. No min-occupancy bound: allocator
// may use up to 256 VGPR (1 block/CU, 8 waves - R7 showed TLP isn't binding).
__global__ __launch_bounds__(512) void k_pass2(const _Float16* __restrict__ xf,
                                               const _Float16* __restrict__ xt,
                                               const float* __restrict__ c2,
                                               const float* __restrict__ x,
                                               const float* __restrict__ gamma,
                                               float* __restrict__ out) {
    const int tid = threadIdx.x;
    const int wave = tid >> 6, lane = tid & 63;
    const int quad = lane >> 4, l15 = lane & 15;
    const int ih = blockIdx.x & 1;
    const int j0 = ((blockIdx.x >> 1) & 63) * 64;
    const int b  = blockIdx.x >> 7;
    const _Float16* xb  = xf + (size_t)b * NN * CC;
    const _Float16* xtb = xt + (size_t)b * CC * NN;   // XT2 [n/32][c][32]
    const float* c2b = c2 + b * NN;

    __shared__ float red[8][64][32];   // 64 KB

    const int addrLo = (((quad & 1) << 5) + l15) << 2;
    const int addrHi = addrLo + 64;
    const bool lo32 = (lane < 32);

    const half8 bj0 = *(const half8*)(xb + (size_t)(j0 + l15) * CC + quad * 8);
    const half8 bj1 = *(const half8*)(xb + (size_t)(j0 + 16 + l15) * CC + quad * 8);
    const half8 bj2 = *(const half8*)(xb + (size_t)(j0 + 32 + l15) * CC + quad * 8);
    const half8 bj3 = *(const half8*)(xb + (size_t)(j0 + 48 + l15) * CC + quad * 8);
    const float4v zf = {0.f, 0.f, 0.f, 0.f};
    float4v acc00 = zf, acc01 = zf, acc10 = zf, acc11 = zf;
    float4v acc20 = zf, acc21 = zf, acc30 = zf, acc31 = zf;

    const int ibase = ih * 2048 + wave * 256;
    half8 a0  = *(const half8*)(xb + (size_t)(ibase + l15) * CC + quad * 8);
    half8 a1  = *(const half8*)(xb + (size_t)(ibase + 16 + l15) * CC + quad * 8);
    half8 xb0 = *(const half8*)(xtb + (size_t)ibase * 32 + l15 * 32 + quad * 8);
    half8 xb1 = *(const half8*)(xtb + (size_t)ibase * 32 + (l15 + 16) * 32 + quad * 8);
    float4v c20 = *(const float4v*)(c2b + ibase + quad * 4);
    float4v c21 = *(const float4v*)(c2b + ibase + 16 + quad * 4);

    for (int it = 0; it < 8; ++it) {
        const int inx = ibase + ((it + 1) & 7) * 32;   // wraps on last iter
        half8 na0  = *(const half8*)(xb + (size_t)(inx + l15) * CC + quad * 8);
        half8 na1  = *(const half8*)(xb + (size_t)(inx + 16 + l15) * CC + quad * 8);
        half8 nxb0 = *(const half8*)(xtb + (size_t)inx * 32 + l15 * 32 + quad * 8);
        half8 nxb1 = *(const half8*)(xtb + (size_t)inx * 32 + (l15 + 16) * 32 + quad * 8);
        float4v nc20 = *(const float4v*)(c2b + inx + quad * 4);
        float4v nc21 = *(const float4v*)(c2b + inx + 16 + quad * 4);

        // ---- all 8 S-MFMAs (4 independent j-subtile chains) ----
        float4v s00 = __builtin_amdgcn_mfma_f32_16x16x32_f16(a0, bj0, zf, 0, 0, 0);
        float4v s10 = __builtin_amdgcn_mfma_f32_16x16x32_f16(a1, bj0, zf, 0, 0, 0);
        float4v s01 = __builtin_amdgcn_mfma_f32_16x16x32_f16(a0, bj1, zf, 0, 0, 0);
        float4v s11 = __builtin_amdgcn_mfma_f32_16x16x32_f16(a1, bj1, zf, 0, 0, 0);
        float4v s02 = __builtin_amdgcn_mfma_f32_16x16x32_f16(a0, bj2, zf, 0, 0, 0);
        float4v s12 = __builtin_amdgcn_mfma_f32_16x16x32_f16(a1, bj2, zf, 0, 0, 0);
        float4v s03 = __builtin_amdgcn_mfma_f32_16x16x32_f16(a0, bj3, zf, 0, 0, 0);
        float4v s13 = __builtin_amdgcn_mfma_f32_16x16x32_f16(a1, bj3, zf, 0, 0, 0);

        // ---- all 32 exps ----
        float4v e00, e10, e01, e11, e02, e12, e03, e13;
#pragma unroll
        for (int r = 0; r < 4; ++r) {
            e00[r] = __builtin_amdgcn_exp2f(fmaf(s00[r], L2E, c20[r]));
            e10[r] = __builtin_amdgcn_exp2f(fmaf(s10[r], L2E, c21[r]));
            e01[r] = __builtin_amdgcn_exp2f(fmaf(s01[r], L2E, c20[r]));
            e11[r] = __builtin_amdgcn_exp2f(fmaf(s11[r], L2E, c21[r]));
            e02[r] = __builtin_amdgcn_exp2f(fmaf(s02[r], L2E, c20[r]));
            e12[r] = __builtin_amdgcn_exp2f(fmaf(s12[r], L2E, c21[r]));
            e03[r] = __builtin_amdgcn_exp2f(fmaf(s03[r], L2E, c20[r]));
            e13[r] = __builtin_amdgcn_exp2f(fmaf(s13[r], L2E, c21[r]));
        }

        // ---- 4 transposes + 8 PV-MFMAs (independent; scheduler interleaves) ----
        {
            const int d0 = __builtin_bit_cast(int, (half2v)__builtin_amdgcn_cvt_pkrtz(e00[0], e00[1]));
            const int d1 = __builtin_bit_cast(int, (half2v)__builtin_amdgcn_cvt_pkrtz(e00[2], e00[3]));
            const int d2 = __builtin_bit_cast(int, (half2v)__builtin_amdgcn_cvt_pkrtz(e10[0], e10[1]));
            const int d3 = __builtin_bit_cast(int, (half2v)__builtin_amdgcn_cvt_pkrtz(e10[2], e10[3]));
            const int q0 = __builtin_amdgcn_ds_bpermute(addrLo, d0);
            const int q1 = __builtin_amdgcn_ds_bpermute(addrLo, d1);
            const int q2 = __builtin_amdgcn_ds_bpermute(addrHi, d0);
            const int q3 = __builtin_amdgcn_ds_bpermute(addrHi, d1);
            const int q4 = __builtin_amdgcn_ds_bpermute(addrLo, d2);
            const int q5 = __builtin_amdgcn_ds_bpermute(addrLo, d3);
            const int q6 = __builtin_amdgcn_ds_bpermute(addrHi, d2);
            const int q7 = __builtin_amdgcn_ds_bpermute(addrHi, d3);
            int4v ai;
            ai[0] = lo32 ? q0 : q4;
            ai[1] = lo32 ? q1 : q5;
            ai[2] = lo32 ? q2 : q6;
            ai[3] = lo32 ? q3 : q7;
            const half8 a2 = __builtin_bit_cast(half8, ai);   // P^T[j=j0+l15][i32]
            acc00 = __builtin_amdgcn_mfma_f32_16x16x32_f16(a2, xb0, acc00, 0, 0, 0);
            acc01 = __builtin_amdgcn_mfma_f32_16x16x32_f16(a2, xb1, acc01, 0, 0, 0);
        }
        {
            const int d0 = __builtin_bit_cast(int, (half2v)__builtin_amdgcn_cvt_pkrtz(e01[0], e01[1]));
            const int d1 = __builtin_bit_cast(int, (half2v)__builtin_amdgcn_cvt_pkrtz(e01[2], e01[3]));
            const int d2 = __builtin_bit_cast(int, (half2v)__builtin_amdgcn_cvt_pkrtz(e11[0], e11[1]));
            const int d3 = __builtin_bit_cast(int, (half2v)__builtin_amdgcn_cvt_pkrtz(e11[2], e11[3]));
            const int q0 = __builtin_amdgcn_ds_bpermute(addrLo, d0);
            const int q1 = __builtin_amdgcn_ds_bpermute(addrLo, d1);
            const int q2 = __builtin_amdgcn_ds_bpermute(addrHi, d0);
            const int q3 = __builtin_amdgcn_ds_bpermute(addrHi, d1);
            const int q4 = __builtin_amdgcn_ds_bpermute(addrLo, d2);
            const int q5 = __builtin_amdgcn_ds_bpermute(addrLo, d3);
            const int q6 = __builtin_amdgcn_ds_bpermute(addrHi, d2);
            const int q7 = __builtin_amdgcn_ds_bpermute(addrHi, d3);
            int4v ai;
            ai[0] = lo32 ? q0 : q4;
            ai[1] = lo32 ? q1 : q5;
            ai[2] = lo32 ? q2 : q6;
            ai[3] = lo32 ? q3 : q7;
            const half8 a2 = __builtin_bit_cast(half8, ai);   // P^T[j=j0+16+l15][i32]
            acc10 = __builtin_amdgcn_mfma_f32_16x16x32_f16(a2, xb0, acc10, 0, 0, 0);
            acc11 = __builtin_amdgcn_mfma_f32_16x16x32_f16(a2, xb1, acc11, 0, 0, 0);
        }
        {
            const int d0 = __builtin_bit_cast(int, (half2v)__builtin_amdgcn_cvt_pkrtz(e02[0], e02[1]));
            const int d1 = __builtin_bit_cast(int, (half2v)__builtin_amdgcn_cvt_pkrtz(e02[2], e02[3]));
            const int d2 = __builtin_bit_cast(int, (half2v)__builtin_amdgcn_cvt_pkrtz(e12[0], e12[1]));
            const int d3 = __builtin_bit_cast(int, (half2v)__builtin_amdgcn_cvt_pkrtz(e12[2], e12[3]));
            const int q0 = __builtin_amdgcn_ds_bpermute(addrLo, d0);
            const int q1 = __builtin_amdgcn_ds_bpermute(addrLo, d1);
            const int q2 = __builtin_amdgcn_ds_bpermute(addrHi, d0);
            const int q3 = __builtin_amdgcn_ds_bpermute(addrHi, d1);
            const int q4 = __builtin_amdgcn_ds_bpermute(addrLo, d2);
            const int q5 = __builtin_amdgcn_ds_bpermute(addrLo, d3);
            const int q6 = __builtin_amdgcn_ds_bpermute(addrHi, d2);
            const int q7 = __builtin_amdgcn_ds_bpermute(addrHi, d3);
            int4v ai;
            ai[0] = lo32 ? q0 : q4;
            ai[1] = lo32 ? q1 : q5;
            ai[2] = lo32 ? q2 : q6;
            ai[3] = lo32 ? q3 : q7;
            const half8 a2 = __builtin_bit_cast(half8, ai);   // P^T[j=j0+32+l15][i32]
            acc20 = __builtin_amdgcn_mfma_f32_16x16x32_f16(a2, xb0, acc20, 0, 0, 0);
            acc21 = __builtin_amdgcn_mfma_f32_16x16x32_f16(a2, xb1, acc21, 0, 0, 0);
        }
        {
            const int d0 = __builtin_bit_cast(int, (half2v)__builtin_amdgcn_cvt_pkrtz(e03[0], e03[1]));
            const int d1 = __builtin_bit_cast(int, (half2v)__builtin_amdgcn_cvt_pkrtz(e03[2], e03[3]));
            const int d2 = __builtin_bit_cast(int, (half2v)__builtin_amdgcn_cvt_pkrtz(e13[0], e13[1]));
            const int d3 = __builtin_bit_cast(int, (half2v)__builtin_amdgcn_cvt_pkrtz(e13[2], e13[3]));
            const int q0 = __builtin_amdgcn_ds_bpermute(addrLo, d0);
            const int q1 = __builtin_amdgcn_ds_bpermute(addrLo, d1);
            const int q2 = __builtin_amdgcn_ds_bpermute(addrHi, d0);
            const int q3 = __builtin_amdgcn_ds_bpermute(addrHi, d1);
            const int q4 = __builtin_amdgcn_ds_bpermute(addrLo, d2);
            const int q5 = __builtin_amdgcn_ds_bpermute(addrLo, d3);
            const int q6 = __builtin_amdgcn_ds_bpermute(addrHi, d2);
            const int q7 = __builtin_amdgcn_ds_bpermute(addrHi, d3);
            int4v ai;
            ai[0] = lo32 ? q0 : q4;
            ai[1] = lo32 ? q1 : q5;
            ai[2] = lo32 ? q2 : q6;
            ai[3] = lo32 ? q3 : q7;
            const half8 a2 = __builtin_bit_cast(half8, ai);   // P^T[j=j0+48+l15][i32]
            acc30 = __builtin_amdgcn_mfma_f32_16x16x32_f16(a2, xb0, acc30, 0, 0, 0);
            acc31 = __builtin_amdgcn_mfma_f32_16x16x32_f16(a2, xb1, acc31, 0, 0, 0);
        }

        a0 = na0; a1 = na1; xb0 = nxb0; xb1 = nxb1; c20 = nc20; c21 = nc21;
    }

    // 8-wave LDS reduction, then one atomicAdd per output element
#pragma unroll
    for (int r = 0; r < 4; ++r) {
        red[wave][quad * 4 + r][l15]           = acc00[r];
        red[wave][quad * 4 + r][l15 + 16]      = acc01[r];
        red[wave][16 + quad * 4 + r][l15]      = acc10[r];
        red[wave][16 + quad * 4 + r][l15 + 16] = acc11[r];
        red[wave][32 + quad * 4 + r][l15]      = acc20[r];
        red[wave][32 + quad * 4 + r][l15 + 16] = acc21[r];
        red[wave][48 + quad * 4 + r][l15]      = acc30[r];
        red[wave][48 + quad * 4 + r][l15 + 16] = acc31[r];
    }
    __syncthreads();
    {
        const int jj = tid >> 5, c = tid & 31;   // 512 threads: 16 j x 32 c, x4
        const float g = gamma[0];
#pragma unroll
        for (int h = 0; h < 4; ++h) {
            const int j = jj + h * 16;
            float s = 0.f;
#pragma unroll
            for (int w = 0; w < 8; ++w) s += red[w][j][c];
            const size_t o = (size_t)(b * NN + j0 + j) * CC + c;
            float v = g * s;
            if (ih == 0) v += x[o];              // add the residual exactly once
            atomicAdd(&out[o], v);
        }
    }
}

extern "C" void kernel_launch(void* const* d_in, const int* in_sizes, int n_in,
                              void* d_out, int out_size, void* d_ws, size_t ws_size,
                              hipStream_t stream) {
    const float* x     = (const float*)d_in[0];
    const float* gamma = (const float*)d_in[1];
    float* out = (float*)d_out;

    // ws layout: Xf16 (512 KB) | XT2 f16 (512 KB) | c2 fp32 (32 KB)
    _Float16* xf = (_Float16*)d_ws;
    _Float16* xt = xf + (size_t)2 * NN * CC;
    float*    c2 = (float*)(xt + (size_t)2 * CC * NN);

    k_convert<<<dim3(256), dim3(256), 0, stream>>>(x, xf, xt, out);
    k_pass1 <<<dim3(256), dim3(512), 0, stream>>>(xf, c2);
    k_pass2 <<<dim3(256), dim3(512), 0, stream>>>(xf, xt, c2, x, gamma, out);
}